// Round 11
// baseline (143.239 us; speedup 1.0000x reference)
//
#include <hip/hip_runtime.h>
#include <math.h>

#define B_    8
#define Q_    900
#define NCLS_ 11
#define NANC_ 100
#define H_    200
#define W_    200
#define C_    256
#define M_    (H_ * W_)     // 40000 pixels per batch image
#define KPAD_ 120           // LDS k-stride (f16): 240B rows -> 2-way banks (free)
#define MT_   128           // pixels per block (8 waves x 16)
#define NTILE_ 313          // ceil(40000/128)

typedef _Float16 half8_ __attribute__((ext_vector_type(8)));
typedef _Float16 half4_ __attribute__((ext_vector_type(4)));
typedef float    f32x4_ __attribute__((ext_vector_type(4)));

// ---------------------------------------------------------------------------
// Kernel 1: scores + rank-based top-k + box->pixel coords (one block per batch)
// (unchanged — proven rounds 1-10)
// ---------------------------------------------------------------------------
__global__ __launch_bounds__(1024) void segdet_topk_kernel(
    const float* __restrict__ pred_boxes,   // [B,Q,4]
    const float* __restrict__ pred_logits,  // [B,Q,NCLS]
    const float* __restrict__ view,         // [B,5,5]
    int*  __restrict__ ws_idx,              // [B,NANC]  selected q index
    int4* __restrict__ ws_box)              // [B,NANC]  (x0,y0,x1,y1) clipped ints
{
    const int b = blockIdx.x;
    const int q = threadIdx.x;

    __shared__ float sc[Q_];

    if (q < Q_) {
        const float* l = pred_logits + (b * Q_ + q) * NCLS_;
        float v[NCLS_];
        float m = -INFINITY;
        #pragma unroll
        for (int i = 0; i < NCLS_; ++i) { v[i] = l[i]; m = fmaxf(m, v[i]); }
        float s = 0.0f, e10 = -INFINITY;
        #pragma unroll
        for (int i = 0; i < NCLS_; ++i) {
            float e = expf(v[i] - m);
            s += e;
            if (i < NCLS_ - 1) e10 = fmaxf(e10, e);   // exclude background (last)
        }
        sc[q] = e10 / s;
    }
    __syncthreads();

    if (q < Q_) {
        const float my = sc[q];
        int rank = 0;
        for (int j = 0; j < Q_; ++j) {
            float o = sc[j];
            rank += (o > my) || (o == my && j < q);   // top_k tie-break: lower idx first
        }
        if (rank < NANC_) {
            // box -> xyxy -> view transform -> trunc int -> clip, in double so the
            // int-truncation boundary matches the reference exactly.
            const float* bx = pred_boxes + (b * Q_ + q) * 4;
            double cx = (double)bx[0], cy = (double)bx[1];
            double w  = exp((double)bx[2]);
            double h  = exp((double)bx[3]);
            double p[5] = { cx - 0.5 * w, cy - 0.5 * h,
                            cx + 0.5 * w, cy + 0.5 * h, 1.0 };
            const float* v5 = view + b * 25;
            int ico[4];
            #pragma unroll
            for (int i = 0; i < 4; ++i) {
                double acc = 0.0;
                #pragma unroll
                for (int j = 0; j < 5; ++j) acc += (double)v5[i * 5 + j] * p[j];
                ico[i] = (int)acc;                    // trunc toward zero == astype(int32)
            }
            int x0 = min(max(ico[0], 0), W_);
            int y0 = min(max(ico[1], 0), H_);
            int x1 = min(max(ico[2], 0), W_);
            int y1 = min(max(ico[3], 0), H_);
            const int slot = b * NANC_ + rank;        // rank unique -> no atomics
            ws_idx[slot] = q;
            ws_box[slot] = make_int4(x0, y0, x1, y1);
        }
    }
}

// ---------------------------------------------------------------------------
// Kernel 2: BEV splat as MFMA GEMM.  bev[b] = region[b] @ feats[b]:
//   D[ch][px] = sum_k feats_f16[ch][k] * region[k][px]
// Block = 512 threads (8 waves), 128 pixels; feats[b] staged once into LDS as
// F[256ch][KPAD_ k] f16 (stride 120 -> conflict-free ds_read_b128); region
// fragments built in registers from 100 box coords (sentinel-padded to 128).
// D-layout (verified): col=lane&15 (px), row=(lane>>4)*4+reg (ch) -> each
// lane's 4 acc regs are 4 consecutive channels = float4 store.
// k-slot mapping of A/B frags is symmetric -> any bijective k map is correct.
// Uncovered px -> region row all 0 -> exact 0 output. Mask = OR of bits.
// No per-row preamble, no event walk, no serial loads, uniform blocks.
// ---------------------------------------------------------------------------
__global__ __launch_bounds__(512, 4) void segdet_gemm_kernel(
    const float* __restrict__ box_feats,    // [B,Q,C]
    const int*   __restrict__ ws_idx,       // [B,NANC]
    const int4*  __restrict__ ws_box,       // [B,NANC]
    float* __restrict__ bev,                // [B,H,W,C]
    float* __restrict__ mask)               // [B,H,W] (0/1 floats)
{
    const int blk = blockIdx.x;
    const int b   = blk / NTILE_;
    const int mt  = blk % NTILE_;
    const int tid = threadIdx.x;
    const int ln  = tid & 63;
    const int wv  = tid >> 6;

    __shared__ __align__(16) _Float16 sF[C_ * KPAD_ + 64];  // +64 zero pad (OOB k-reads)
    __shared__ int sB[128];                                 // x0|y0<<8|x1<<16|y1<<24

    // ---- stage boxes (sentinels never cover: x0=255 > any w)
    if (tid < 128) {
        int packed = 0x0000FFFF;
        if (tid < NANC_) {
            int4 bx = ws_box[b * NANC_ + tid];
            packed = bx.x | (bx.y << 8) | (bx.z << 16) | (bx.w << 24);
        }
        sB[tid] = packed;
    }
    if (tid < 64) sF[C_ * KPAD_ + tid] = (_Float16)0.0f;    // zero the tail pad

    // ---- stage feats f32 -> f16 into F[ch][k] (k-quads; zeros for k>=100)
    for (int it = tid; it < C_ * (KPAD_ / 4); it += 512) {
        const int kq = it / C_;             // 0..29 (k quad)
        const int ch = it % C_;             // coalesced across threads
        half4_ v = { (_Float16)0.0f, (_Float16)0.0f, (_Float16)0.0f, (_Float16)0.0f };
        if (kq < NANC_ / 4) {
            #pragma unroll
            for (int j = 0; j < 4; ++j) {
                const int k = kq * 4 + j;
                const int q = ws_idx[b * NANC_ + k];
                v[j] = (_Float16)box_feats[((size_t)b * Q_ + q) * C_ + ch];
            }
        }
        *(half4_*)&sF[ch * KPAD_ + kq * 4] = v;
    }
    __syncthreads();

    // ---- this wave's 16 pixels
    const int pxbase = mt * MT_ + wv * 16;
    if (pxbase >= M_) return;               // OOB tail waves (after the barrier)

    const int m0 = pxbase + (ln & 15);      // lane's pixel (B-operand col / D col)
    const int hh = m0 / W_;
    const int ww = m0 % W_;
    const int kg = (ln >> 4) * 8;           // lane's k-octet base within a K=32 step

    f32x4_ acc[16];
    #pragma unroll
    for (int i = 0; i < 16; ++i) acc[i] = (f32x4_){0.f, 0.f, 0.f, 0.f};
    int mor = 0;

    #pragma unroll
    for (int ks = 0; ks < 4; ++ks) {
        // region fragment (B-operand): n = ln&15 (px), k-slot = kg + j
        half8_ rb;
        #pragma unroll
        for (int j = 0; j < 8; ++j) {
            const int k  = ks * 32 + kg + j;          // < 128; sentinels for k>=100
            const int pk = sB[k];
            const int x0 = pk & 0xFF, y0 = (pk >> 8) & 0xFF;
            const int x1 = (pk >> 16) & 0xFF, y1 = (pk >> 24) & 0xFF;
            const bool cov = (x0 <= ww) & (ww < x1) & (y0 <= hh) & (hh < y1);
            rb[j] = (_Float16)(cov ? 1.0f : 0.0f);
            mor |= (int)cov;
        }
        // feats fragments (A-operand): m = ln&15 (ch within tile), same k-slots
        #pragma unroll
        for (int ct = 0; ct < 16; ++ct) {
            const half8_ fa = *(const half8_*)&sF[(ct * 16 + (ln & 15)) * KPAD_
                                                  + ks * 32 + kg];
            acc[ct] = __builtin_amdgcn_mfma_f32_16x16x32_f16(fa, rb, acc[ct], 0, 0, 0);
        }
    }

    // ---- store D: lane holds 4 consecutive channels (ch = ct*16+(ln>>4)*4+reg)
    float* orow = bev + ((size_t)b * M_ + m0) * C_ + (ln >> 4) * 4;
    #pragma unroll
    for (int ct = 0; ct < 16; ++ct)
        *(f32x4_*)(orow + ct * 16) = acc[ct];

    // ---- mask: OR region bits across the 4 k-groups, lanes 0..15 store
    mor |= __shfl_xor(mor, 16);
    mor |= __shfl_xor(mor, 32);
    if (ln < 16) mask[(size_t)b * M_ + pxbase + ln] = mor ? 1.0f : 0.0f;
}

// ---------------------------------------------------------------------------
extern "C" void kernel_launch(void* const* d_in, const int* in_sizes, int n_in,
                              void* d_out, int out_size, void* d_ws, size_t ws_size,
                              hipStream_t stream) {
    const float* pred_boxes  = (const float*)d_in[0];
    const float* pred_logits = (const float*)d_in[1];
    const float* box_feats   = (const float*)d_in[2];
    const float* view        = (const float*)d_in[3];

    float* bev  = (float*)d_out;
    float* mask = bev + (size_t)B_ * M_ * C_;

    int*  ws_idx = (int*)d_ws;                            // 800 ints = 3200 B
    int4* ws_box = (int4*)((char*)d_ws + 3200);           // 800 int4 (16B aligned)

    segdet_topk_kernel<<<B_, 1024, 0, stream>>>(pred_boxes, pred_logits, view,
                                                ws_idx, ws_box);
    segdet_gemm_kernel<<<B_ * NTILE_, 512, 0, stream>>>(box_feats, ws_idx, ws_box,
                                                        bev, mask);
}

// Round 12
// 103.089 us; speedup vs baseline: 1.3895x; 1.3895x over previous
//
#include <hip/hip_runtime.h>
#include <math.h>

#define B_    8
#define Q_    900
#define NCLS_ 11
#define NANC_ 100
#define H_    200
#define W_    200
#define C_    256
#define HHALF 100           // split pixel: waves 0,1 -> [0,100), waves 2,3 -> [100,200)
#define CHNK_ 113           // rank chunk per block (8 x 113 >= 900)

typedef float f32x4_ __attribute__((ext_vector_type(4)));   // native vec for nt-store

// ---------------------------------------------------------------------------
// Kernel 1 (fused, distributed): scores + rank + box transform.
// Grid = B_*8 blocks x 128 threads. Each block recomputes ALL 900 scores of
// its batch image into LDS (logits are L2-resident, 40KB/block), then ranks
// its own 113-query chunk via float4 LDS scans (225 b128 broadcasts vs the
// old 900 b32 serial chain on 8 CUs). Same formula, same tie-break, same
// double-precision transform as rounds 1-11 (absmax-proven).
// ---------------------------------------------------------------------------
__global__ __launch_bounds__(128) void segdet_topk_kernel(
    const float* __restrict__ pred_boxes,   // [B,Q,4]
    const float* __restrict__ pred_logits,  // [B,Q,NCLS]
    const float* __restrict__ view,         // [B,5,5]
    int*  __restrict__ ws_idx,              // [B,NANC]  selected q index
    int4* __restrict__ ws_box)              // [B,NANC]  (x0,y0,x1,y1) clipped ints
{
    const int b     = blockIdx.x >> 3;
    const int chunk = blockIdx.x & 7;
    const int tid   = threadIdx.x;

    __shared__ __align__(16) float sc[Q_];  // 900 floats (900%4==0 -> b128-clean)

    for (int q2 = tid; q2 < Q_; q2 += 128) {
        const float* l = pred_logits + (b * Q_ + q2) * NCLS_;
        float v[NCLS_];
        float m = -INFINITY;
        #pragma unroll
        for (int i = 0; i < NCLS_; ++i) { v[i] = l[i]; m = fmaxf(m, v[i]); }
        float s = 0.0f, e10 = -INFINITY;
        #pragma unroll
        for (int i = 0; i < NCLS_; ++i) {
            float e = expf(v[i] - m);
            s += e;
            if (i < NCLS_ - 1) e10 = fmaxf(e10, e);   // exclude background (last)
        }
        sc[q2] = e10 / s;
    }
    __syncthreads();

    const int q = chunk * CHNK_ + tid;
    if (tid < CHNK_ && q < Q_) {
        const float my = sc[q];
        int rank = 0;
        #pragma unroll 4
        for (int j4 = 0; j4 < Q_ / 4; ++j4) {          // float4 broadcast scan
            const float4 o = *(const float4*)&sc[j4 * 4];
            const int j = j4 * 4;
            rank += (o.x > my) || (o.x == my && (j + 0) < q);
            rank += (o.y > my) || (o.y == my && (j + 1) < q);
            rank += (o.z > my) || (o.z == my && (j + 2) < q);
            rank += (o.w > my) || (o.w == my && (j + 3) < q);
        }
        if (rank < NANC_) {
            // box -> xyxy -> view transform -> trunc int -> clip, in double so the
            // int-truncation boundary matches the reference exactly.
            const float* bx = pred_boxes + (b * Q_ + q) * 4;
            double cx = (double)bx[0], cy = (double)bx[1];
            double w  = exp((double)bx[2]);
            double h  = exp((double)bx[3]);
            double p[5] = { cx - 0.5 * w, cy - 0.5 * h,
                            cx + 0.5 * w, cy + 0.5 * h, 1.0 };
            const float* v5 = view + b * 25;
            int ico[4];
            #pragma unroll
            for (int i = 0; i < 4; ++i) {
                double acc = 0.0;
                #pragma unroll
                for (int j = 0; j < 5; ++j) acc += (double)v5[i * 5 + j] * p[j];
                ico[i] = (int)acc;                    // trunc toward zero == astype(int32)
            }
            int x0 = min(max(ico[0], 0), W_);
            int y0 = min(max(ico[1], 0), H_);
            int x1 = min(max(ico[2], 0), W_);
            int y1 = min(max(ico[3], 0), H_);
            const int slot = b * NANC_ + rank;        // rank unique -> no atomics
            ws_idx[slot] = q;
            ws_box[slot] = make_int4(x0, y0, x1, y1);
        }
    }
}

__device__ __forceinline__ void nt_store4(float* p, float4 v) {
    f32x4_ nv = { v.x, v.y, v.z, v.w };
    __builtin_nontemporal_store(nv, (f32x4_*)p);     // keep write stream out of L2
}

// ---------------------------------------------------------------------------
// Kernel 2: BEV splat — R10 verbatim (112.97us, best known).
// ---------------------------------------------------------------------------
__global__ __launch_bounds__(256) void segdet_bev_kernel(
    const float* __restrict__ box_feats,    // [B,Q,C]
    const int*   __restrict__ ws_idx,       // [B,NANC]
    const int4*  __restrict__ ws_box,       // [B,NANC]
    float* __restrict__ bev,                // [B,H,W,C]
    float* __restrict__ mask)               // [B,H,W] (0/1 floats)
{
    // center-out row order: hidx 0,1,2,3,... -> h 100,99,101,98,...
    const int hidx = blockIdx.x / B_;
    const int b    = blockIdx.x % B_;
    const int h    = (hidx & 1) ? (HHALF - 1 - (hidx >> 1)) : (HHALF + (hidx >> 1));

    const int tid = threadIdx.x;
    const int ln  = tid & 63;
    const int wv  = tid >> 6;

    __shared__ int s_box[NANC_];            // x0 | x1<<8 | q<<16 (packed)
    __shared__ int s_nact;
    __shared__ int s_nopen[W_];             // # opens at pixel w
    __shared__ int s_ofs[W_ + 1];           // CSR offsets (exclusive scan)
    __shared__ int s_evpos[W_];             // ascending event pixels
    __shared__ int s_ent[2 * NANC_];        // q | (close ? 1<<31 : 0)
    __shared__ int s_wsum[4];               // per-wave ENTRY totals (scan)
    __shared__ int s_wtot[4];               // per-wave event-PIXEL counts
    __shared__ int s_plow;                  // event pixels 64..100 (wave-1 low lanes)

    // ---- wave-0 ballot compaction of row-active anchors (deterministic order)
    if (tid < 64) {
        int na = 0;
        #pragma unroll
        for (int it = 0; it < 2; ++it) {
            int k = it * 64 + ln;
            bool act = false;
            int packed = 0;
            if (k < NANC_) {
                int4 bx = ws_box[b * NANC_ + k];
                int qi  = ws_idx[b * NANC_ + k];
                act = (bx.y <= h) && (h < bx.w) && (bx.x < bx.z);
                packed = bx.x | (bx.z << 8) | (qi << 16);
            }
            unsigned long long ball = __ballot(act);
            int pos = na + (int)__popcll(ball & ((1ull << ln) - 1ull));
            if (act) s_box[pos] = packed;
            na += (int)__popcll(ball);
        }
        if (ln == 0) s_nact = na;
    }
    __syncthreads();                                   // barrier #1

    const int nact = s_nact;
    float* obase = bev + (size_t)(b * H_ + h) * W_ * C_ + ln * 4;
    float* mrow  = mask + (size_t)(b * H_ + h) * W_;

    // ---- empty-row fast path
    if (nact == 0) {
        const float4 z = make_float4(0.f, 0.f, 0.f, 0.f);
        for (int w = wv; w < W_; w += 4)
            nt_store4(obase + (size_t)w * C_, z);
        if (tid < W_) __builtin_nontemporal_store(0.0f, &mrow[tid]);
        return;
    }

    // ---- per-pixel open/close counts + coverage (mask), in parallel
    int ntot = 0;
    if (tid < W_) {
        int nopen = 0, nclose = 0, cov = 0;
        for (int k = 0; k < nact; ++k) {
            int pk = s_box[k];                 // uniform LDS broadcast
            int x0 = pk & 0xFF, x1 = (pk >> 8) & 0xFF;
            nopen  += (x0 == tid);
            nclose += (x1 == tid);             // x1==200 auto-excluded (tid<200)
            cov    += (x0 <= tid) && (tid < x1);
        }
        s_nopen[tid] = nopen;
        ntot = nopen + nclose;
        __builtin_nontemporal_store((cov > 0) ? 1.0f : 0.0f, &mrow[tid]);
    }

    // ---- shuffle-based inclusive scan of entry counts (6 steps, in-wave)
    int incl = ntot;
    #pragma unroll
    for (int d = 1; d < 64; d <<= 1) {
        int u = __shfl_up(incl, d);
        incl = (ln >= d) ? incl + u : incl;
    }
    if (ln == 63) s_wsum[wv] = incl;

    // ---- event-pixel ballot (flag = any entry at this pixel)
    const bool flag = (tid < W_) && (ntot > 0);
    const unsigned long long bal = __ballot(flag);
    if (ln == 0) s_wtot[wv] = (int)__popcll(bal);
    if (wv == 1 && ln == 0)                            // lanes 0..36 = pixels 64..100
        s_plow = (int)__popcll(bal & ((1ull << 37) - 1ull));
    __syncthreads();                                   // barrier #2

    int prev = 0;
    #pragma unroll
    for (int j = 0; j < 4; ++j) prev += (j < wv) ? s_wsum[j] : 0;
    const int ne = s_wsum[0] + s_wsum[1] + s_wsum[2] + s_wsum[3];
    if (tid < W_) s_ofs[tid] = prev + incl - ntot;     // exclusive entry scan
    if (tid == 0) s_ofs[W_] = ne;

    const int nev = s_wtot[0] + s_wtot[1] + s_wtot[2] + s_wtot[3];
    int eoff = 0;
    #pragma unroll
    for (int j = 0; j < 4; ++j) eoff += (j < wv) ? s_wtot[j] : 0;
    if (flag) s_evpos[eoff + (int)__popcll(bal & ((1ull << ln) - 1ull))] = tid;
    __syncthreads();                                   // barrier #3 (s_ofs ready)

    // ---- CSR entry scatter: one thread per active box, stable k-order
    if (tid < nact) {
        int pk = s_box[tid];
        int x0 = pk & 0xFF, x1 = (pk >> 8) & 0xFF, q = pk >> 16;
        int ro = 0, rc = 0;
        for (int j = 0; j < tid; ++j) {
            int pj = s_box[j];
            ro += ((pj & 0xFF) == x0);
            rc += (((pj >> 8) & 0xFF) == x1);
        }
        s_ent[s_ofs[x0] + ro] = q;                                        // open
        if (x1 < W_) s_ent[s_ofs[x1] + s_nopen[x1] + rc] = q | (1 << 31); // close
    }
    __syncthreads();                                   // barrier #4

    // ---- half-split walk: waves 0,1 -> [0,100) stride 2; waves 2,3 -> [100,200)
    const bool upper = (wv >= 2);
    const int  wbeg  = upper ? (HHALF + (wv - 2)) : wv;
    const int  wlim  = upper ? W_ : HHALF;
    const int  p_lo  = s_wtot[0] + s_plow;             // # event pixels <= HHALF

    const float* fbase = box_feats + (size_t)b * Q_ * C_ + ln * 4;

    float4 acc = make_float4(0.f, 0.f, 0.f, 0.f);
    int cnt = 0;
    if (upper) {
        // init: coverage state at pixel HHALF (k-order; independent loads)
        for (int k = 0; k < nact; ++k) {
            int pk = s_box[k];
            int x0 = pk & 0xFF, x1 = (pk >> 8) & 0xFF;
            if (x0 <= HHALF && HHALF < x1) {
                const float4 f = *(const float4*)(fbase + (size_t)(pk >> 16) * C_);
                acc.x += f.x; acc.y += f.y; acc.z += f.z; acc.w += f.w;
                ++cnt;
            }
        }
    }
    int p = upper ? p_lo : 0;
    int nextpix = (p < nev) ? s_evpos[p] : W_;
    for (int w = wbeg; w < wlim; w += 2) {
        while (w >= nextpix) {                         // apply events passed
            int e1 = s_ofs[nextpix + 1];
            for (int e = s_ofs[nextpix]; e < e1; ++e) {
                int ent = s_ent[e];                    // uniform broadcast
                int q = ent & 0xFFFF;
                const float4 f = *(const float4*)(fbase + (size_t)q * C_);
                if (ent < 0) { acc.x -= f.x; acc.y -= f.y; acc.z -= f.z; acc.w -= f.w; --cnt; }
                else         { acc.x += f.x; acc.y += f.y; acc.z += f.z; acc.w += f.w; ++cnt; }
            }
            ++p;
            nextpix = (p < nev) ? s_evpos[p] : W_;
        }
        if (cnt == 0) acc = make_float4(0.f, 0.f, 0.f, 0.f);  // exact zeros
        nt_store4(obase + (size_t)w * C_, acc);
    }
}

// ---------------------------------------------------------------------------
extern "C" void kernel_launch(void* const* d_in, const int* in_sizes, int n_in,
                              void* d_out, int out_size, void* d_ws, size_t ws_size,
                              hipStream_t stream) {
    const float* pred_boxes  = (const float*)d_in[0];
    const float* pred_logits = (const float*)d_in[1];
    const float* box_feats   = (const float*)d_in[2];
    const float* view        = (const float*)d_in[3];

    float* bev  = (float*)d_out;
    float* mask = bev + (size_t)B_ * H_ * W_ * C_;

    int*  ws_idx = (int*)d_ws;                            // 800 ints = 3200 B
    int4* ws_box = (int4*)((char*)d_ws + 3200);           // 800 int4 (16B aligned)

    segdet_topk_kernel<<<B_ * 8, 128, 0, stream>>>(pred_boxes, pred_logits, view,
                                                   ws_idx, ws_box);
    segdet_bev_kernel<<<B_ * H_, 256, 0, stream>>>(box_feats, ws_idx, ws_box,
                                                   bev, mask);
}

// Round 13
// 100.995 us; speedup vs baseline: 1.4183x; 1.0207x over previous
//
#include <hip/hip_runtime.h>
#include <math.h>

#define B_    8
#define Q_    900
#define NCLS_ 11
#define NANC_ 100
#define H_    200
#define W_    200
#define C_    256
#define HHALF 100
#define CHNK_ 113           // rank chunk per block (8 x 113 >= 900)
#define CHEV_ 16            // events per staged chunk (16 x 1KB = 16KB per buffer)

typedef float f32x4_ __attribute__((ext_vector_type(4)));

// ---------------------------------------------------------------------------
// Kernel 1 (fused, distributed): scores + rank + box transform. (R12, proven)
// ---------------------------------------------------------------------------
__global__ __launch_bounds__(128) void segdet_topk_kernel(
    const float* __restrict__ pred_boxes,   // [B,Q,4]
    const float* __restrict__ pred_logits,  // [B,Q,NCLS]
    const float* __restrict__ view,         // [B,5,5]
    int*  __restrict__ ws_idx,              // [B,NANC]
    int4* __restrict__ ws_box)              // [B,NANC]
{
    const int b     = blockIdx.x >> 3;
    const int chunk = blockIdx.x & 7;
    const int tid   = threadIdx.x;

    __shared__ __align__(16) float sc[Q_];

    for (int q2 = tid; q2 < Q_; q2 += 128) {
        const float* l = pred_logits + (b * Q_ + q2) * NCLS_;
        float v[NCLS_];
        float m = -INFINITY;
        #pragma unroll
        for (int i = 0; i < NCLS_; ++i) { v[i] = l[i]; m = fmaxf(m, v[i]); }
        float s = 0.0f, e10 = -INFINITY;
        #pragma unroll
        for (int i = 0; i < NCLS_; ++i) {
            float e = expf(v[i] - m);
            s += e;
            if (i < NCLS_ - 1) e10 = fmaxf(e10, e);
        }
        sc[q2] = e10 / s;
    }
    __syncthreads();

    const int q = chunk * CHNK_ + tid;
    if (tid < CHNK_ && q < Q_) {
        const float my = sc[q];
        int rank = 0;
        #pragma unroll 4
        for (int j4 = 0; j4 < Q_ / 4; ++j4) {
            const float4 o = *(const float4*)&sc[j4 * 4];
            const int j = j4 * 4;
            rank += (o.x > my) || (o.x == my && (j + 0) < q);
            rank += (o.y > my) || (o.y == my && (j + 1) < q);
            rank += (o.z > my) || (o.z == my && (j + 2) < q);
            rank += (o.w > my) || (o.w == my && (j + 3) < q);
        }
        if (rank < NANC_) {
            const float* bx = pred_boxes + (b * Q_ + q) * 4;
            double cx = (double)bx[0], cy = (double)bx[1];
            double w  = exp((double)bx[2]);
            double h  = exp((double)bx[3]);
            double p[5] = { cx - 0.5 * w, cy - 0.5 * h,
                            cx + 0.5 * w, cy + 0.5 * h, 1.0 };
            const float* v5 = view + b * 25;
            int ico[4];
            #pragma unroll
            for (int i = 0; i < 4; ++i) {
                double acc = 0.0;
                #pragma unroll
                for (int j = 0; j < 5; ++j) acc += (double)v5[i * 5 + j] * p[j];
                ico[i] = (int)acc;                    // trunc == astype(int32)
            }
            int x0 = min(max(ico[0], 0), W_);
            int y0 = min(max(ico[1], 0), H_);
            int x1 = min(max(ico[2], 0), W_);
            int y1 = min(max(ico[3], 0), H_);
            const int slot = b * NANC_ + rank;
            ws_idx[slot] = q;
            ws_box[slot] = make_int4(x0, y0, x1, y1);
        }
    }
}

__device__ __forceinline__ void nt_store4(float* p, f32x4_ v) {
    __builtin_nontemporal_store(v, (f32x4_*)p);
}

__device__ __forceinline__ void gload_lds_16(const float* g, float* l) {
    // async global->LDS: per-lane global src, wave-uniform LDS base + lane*16
    __builtin_amdgcn_global_load_lds(
        (const __attribute__((address_space(1))) void*)g,
        (__attribute__((address_space(3))) void*)l,
        16, 0, 0);
}

// ---------------------------------------------------------------------------
// Kernel 2: BEV splat — chunked async event pipeline.
// Mechanism: loads and stores share the in-order vmcnt counter, so any
// in-walk global load consumed after a dynamic store loop forces a
// vmcnt(0) STORE-QUEUE DRAIN (~120/row in R4-R12 — the persistent 2x gap).
// Here event feature vectors are staged per 16-event chunk into a 2x16KB LDS
// double-buffer via global_load_lds (async; consumed only after the chunk
// barrier), and the walk reads them with ds_read_b128 on lgkmcnt — which
// stores never touch. Drains drop to 1 per chunk (~9/heavy row).
// Walk keeps R4's balanced interleave (w = wv, wv+4, ...; all waves apply
// all events; no init loops). s_ent carries pixel (pix<<10) so the evpos
// machinery is gone. LDS ~36KB -> 4 blocks/CU (16 waves). Same event order
// as R4-R12 -> identical numerics.
// ---------------------------------------------------------------------------
__global__ __launch_bounds__(256) void segdet_bev_kernel(
    const float* __restrict__ box_feats,    // [B,Q,C]
    const int*   __restrict__ ws_idx,       // [B,NANC]
    const int4*  __restrict__ ws_box,       // [B,NANC]
    float* __restrict__ bev,                // [B,H,W,C]
    float* __restrict__ mask)               // [B,H,W]
{
    // center-out row order (tail packing; neutral-harmless)
    const int hidx = blockIdx.x / B_;
    const int b    = blockIdx.x % B_;
    const int h    = (hidx & 1) ? (HHALF - 1 - (hidx >> 1)) : (HHALF + (hidx >> 1));

    const int tid = threadIdx.x;
    const int ln  = tid & 63;
    const int wv  = tid >> 6;

    __shared__ __align__(16) float s_chunk[2][CHEV_ * C_];  // 32 KB double buffer
    __shared__ int s_box[NANC_];            // x0 | x1<<8 | q<<16
    __shared__ int s_nact;
    __shared__ int s_nopen[W_];
    __shared__ int s_ofs[W_ + 1];
    __shared__ int s_ent[2 * NANC_];        // q(10b) | pix<<10 | (close?1<<31:0)
    __shared__ int s_wsum[4];

    // ---- wave-0 ballot compaction of row-active anchors (deterministic order)
    if (tid < 64) {
        int na = 0;
        #pragma unroll
        for (int it = 0; it < 2; ++it) {
            int k = it * 64 + ln;
            bool act = false;
            int packed = 0;
            if (k < NANC_) {
                int4 bx = ws_box[b * NANC_ + k];
                int qi  = ws_idx[b * NANC_ + k];
                act = (bx.y <= h) && (h < bx.w) && (bx.x < bx.z);
                packed = bx.x | (bx.z << 8) | (qi << 16);
            }
            unsigned long long ball = __ballot(act);
            int pos = na + (int)__popcll(ball & ((1ull << ln) - 1ull));
            if (act) s_box[pos] = packed;
            na += (int)__popcll(ball);
        }
        if (ln == 0) s_nact = na;
    }
    __syncthreads();                                   // B1

    const int nact = s_nact;
    float* obase = bev + (size_t)(b * H_ + h) * W_ * C_ + ln * 4;
    float* mrow  = mask + (size_t)(b * H_ + h) * W_;

    // ---- empty-row fast path
    if (nact == 0) {
        const f32x4_ z = {0.f, 0.f, 0.f, 0.f};
        for (int w = wv; w < W_; w += 4)
            nt_store4(obase + (size_t)w * C_, z);
        if (tid < W_) __builtin_nontemporal_store(0.0f, &mrow[tid]);
        return;
    }

    // ---- per-pixel open/close counts + coverage (mask)
    int ntot = 0;
    if (tid < W_) {
        int nopen = 0, nclose = 0, cov = 0;
        for (int k = 0; k < nact; ++k) {
            int pk = s_box[k];
            int x0 = pk & 0xFF, x1 = (pk >> 8) & 0xFF;
            nopen  += (x0 == tid);
            nclose += (x1 == tid);
            cov    += (x0 <= tid) && (tid < x1);
        }
        s_nopen[tid] = nopen;
        ntot = nopen + nclose;
        __builtin_nontemporal_store((cov > 0) ? 1.0f : 0.0f, &mrow[tid]);
    }

    // ---- shuffle-based inclusive scan of entry counts
    int incl = ntot;
    #pragma unroll
    for (int d = 1; d < 64; d <<= 1) {
        int u = __shfl_up(incl, d);
        incl = (ln >= d) ? incl + u : incl;
    }
    if (ln == 63) s_wsum[wv] = incl;
    __syncthreads();                                   // B2

    int prev = 0;
    #pragma unroll
    for (int j = 0; j < 4; ++j) prev += (j < wv) ? s_wsum[j] : 0;
    const int ne = s_wsum[0] + s_wsum[1] + s_wsum[2] + s_wsum[3];
    if (tid < W_) s_ofs[tid] = prev + incl - ntot;
    if (tid == 0) s_ofs[W_] = ne;
    __syncthreads();                                   // B3 (s_ofs ready)

    // ---- CSR entry scatter (pixel packed into entry), stable k-order
    if (tid < nact) {
        int pk = s_box[tid];
        int x0 = pk & 0xFF, x1 = (pk >> 8) & 0xFF, q = pk >> 16;
        int ro = 0, rc = 0;
        for (int j = 0; j < tid; ++j) {
            int pj = s_box[j];
            ro += ((pj & 0xFF) == x0);
            rc += (((pj >> 8) & 0xFF) == x1);
        }
        s_ent[s_ofs[x0] + ro] = q | (x0 << 10);                            // open
        if (x1 < W_)
            s_ent[s_ofs[x1] + s_nopen[x1] + rc] =
                (int)((unsigned)q | ((unsigned)x1 << 10) | 0x80000000u);   // close
    }
    __syncthreads();                                   // B4 (s_ent ready)

    const float* fbase = box_feats + (size_t)b * Q_ * C_ + ln * 4;
    const int nchunk = (ne + CHEV_ - 1) / CHEV_;

    // stage chunk ci: wave wv stages events base+wv*4 .. +3 (async)
#define STAGE_(CI)                                                            \
    {                                                                         \
        const int base_ = (CI) * CHEV_;                                       \
        float* dst_ = &s_chunk[(CI) & 1][0];                                  \
        _Pragma("unroll")                                                     \
        for (int j = 0; j < 4; ++j) {                                         \
            const int e_ = base_ + wv * 4 + j;                                \
            if (e_ < ne) {                                                    \
                const int q_ = s_ent[e_] & 0x3FF;                             \
                gload_lds_16(fbase + (size_t)q_ * C_,                         \
                             dst_ + (wv * 4 + j) * C_);                       \
            }                                                                 \
        }                                                                     \
    }

    STAGE_(0);
    __syncthreads();                                   // chunk 0 staged

    f32x4_ acc = {0.f, 0.f, 0.f, 0.f};
    int cnt = 0;
    int w = wv;
    for (int ci = 0; ci < nchunk; ++ci) {
        if (ci + 1 < nchunk) STAGE_(ci + 1);           // overlaps walk of ci
        const int ebeg = ci * CHEV_;
        const int eend = (ne < ebeg + CHEV_) ? ne : (ebeg + CHEV_);
        const float* cb = &s_chunk[ci & 1][0];
        for (int e = ebeg; e < eend; ++e) {
            const int ent = s_ent[e];                  // LDS broadcast
            const int pe  = (ent >> 10) & 0xFF;
            for (; w < pe; w += 4)                     // pure store stream
                nt_store4(obase + (size_t)w * C_, acc);
            const f32x4_ f = *(const f32x4_*)&cb[(e - ebeg) * C_ + ln * 4]; // lgkm
            if (ent < 0) { acc -= f; --cnt; }
            else         { acc += f; ++cnt; }
            if (cnt == 0) acc = (f32x4_){0.f, 0.f, 0.f, 0.f};  // exact zeros
        }
        __syncthreads();   // stage ci+1 complete; buf (ci&1) free for ci+2
    }
#undef STAGE_
    for (; w < W_; w += 4)
        nt_store4(obase + (size_t)w * C_, acc);
}

// ---------------------------------------------------------------------------
extern "C" void kernel_launch(void* const* d_in, const int* in_sizes, int n_in,
                              void* d_out, int out_size, void* d_ws, size_t ws_size,
                              hipStream_t stream) {
    const float* pred_boxes  = (const float*)d_in[0];
    const float* pred_logits = (const float*)d_in[1];
    const float* box_feats   = (const float*)d_in[2];
    const float* view        = (const float*)d_in[3];

    float* bev  = (float*)d_out;
    float* mask = bev + (size_t)B_ * H_ * W_ * C_;

    int*  ws_idx = (int*)d_ws;                            // 800 ints
    int4* ws_box = (int4*)((char*)d_ws + 3200);           // 800 int4 (16B aligned)

    segdet_topk_kernel<<<B_ * 8, 128, 0, stream>>>(pred_boxes, pred_logits, view,
                                                   ws_idx, ws_box);
    segdet_bev_kernel<<<B_ * H_, 256, 0, stream>>>(box_feats, ws_idx, ws_box,
                                                   bev, mask);
}